// Round 8
// baseline (198.987 us; speedup 1.0000x reference)
//
#include <hip/hip_runtime.h>
#include <math.h>

#define N_NODES 50000
#define N_EDGES 640000
#define FDIM 128
#define NCLS 16
#define BN_EPS 1e-5f
#define NBG 782           // ceil(50000/64) gemm tiles
#define NBF 625           // fill blocks (4 edges/thread)
#define ELLW 64           // ELL row width (max degree; Poisson(12.8) -> P(>=64) ~ 1e-25)

typedef __attribute__((ext_vector_type(8))) short bf16x8;
typedef __attribute__((ext_vector_type(4))) float f32x4;

// ---- bf16 pack/unpack (RNE) ----
__device__ __forceinline__ unsigned pack_bf16x2(float lo, float hi) {
    unsigned ul = __float_as_uint(lo);
    unsigned uh = __float_as_uint(hi);
    ul += 0x7fff + ((ul >> 16) & 1);
    uh += 0x7fff + ((uh >> 16) & 1);
    return (ul >> 16) | (uh & 0xffff0000u);
}
__device__ __forceinline__ unsigned short bf16_rne(float x) {
    unsigned u = __float_as_uint(x);
    u += 0x7fff + ((u >> 16) & 1);
    return (unsigned short)(u >> 16);
}
__device__ __forceinline__ float bf_lo(unsigned u) { return __uint_as_float(u << 16); }
__device__ __forceinline__ float bf_hi(unsigned u) { return __uint_as_float(u & 0xffff0000u); }

// async 16B global->LDS copy: LDS dest = wave-uniform base + lane*16, global src per-lane
__device__ __forceinline__ void async_copy16(const void* g, void* l) {
    __builtin_amdgcn_global_load_lds(
        (const __attribute__((address_space(1))) unsigned*)g,
        (__attribute__((address_space(3))) unsigned*)l, 16, 0, 0);
}

// ============ K0: pack W1 frags + fold W2@Wc / BN affine + zero deg ============
// WPK layout: chunks 0..2047 = hi frags, 2048..4095 = lo frags (16B each, fragment order).
// frag index fi = ct*256 + kt*64 + lane; entry j: W1[kt*32+(lane>>4)*8+j][ct*16+(lane&15)]
__global__ __launch_bounds__(256) void pack_fold_zero_kernel(
        const float* __restrict__ W1, const float* __restrict__ W2,
        const float* __restrict__ Wc, const float* __restrict__ b1,
        const float* __restrict__ b2, const float* __restrict__ bc,
        const float* __restrict__ gamma, const float* __restrict__ beta,
        const float* __restrict__ rmean, const float* __restrict__ rvar,
        bf16x8* __restrict__ WPK,
        float* __restrict__ W2c, float* __restrict__ bc2, float4* __restrict__ fusedq,
        uint4* __restrict__ degz) {
    int tid = threadIdx.x;
    int bid = blockIdx.x;

    // -------- zero deg[] (50176 ints = 12544 uint4) across all 16 blocks --------
    {
        int gz = bid * 256 + tid;                   // 0..4095
#pragma unroll
        for (int i = 0; i < 4; i++) {
            int idx = gz + i * 4096;
            if (idx < 12544) degz[idx] = make_uint4(0, 0, 0, 0);
        }
    }

    if (bid >= 8) {
        // -------- pack W1: blocks 8..15, one fragment per thread --------
        int fi = (bid - 8) * 256 + tid;             // 0..2047
        int lane = fi & 63, kt = (fi >> 6) & 3, ct = fi >> 8;
        int kbase = kt * 32 + (lane >> 4) * 8;
        int col = ct * 16 + (lane & 15);
        short h[8], lo[8];
#pragma unroll
        for (int j = 0; j < 8; j++) {
            float wv = W1[(kbase + j) * 128 + col];
            unsigned short hs = bf16_rne(wv);
            float rem = wv - __uint_as_float(((unsigned)hs) << 16);
            h[j] = (short)hs;
            lo[j] = (short)bf16_rne(rem);
        }
        WPK[fi] = *(bf16x8*)h;
        WPK[2048 + fi] = *(bf16x8*)lo;
    } else {
        // -------- fold: W2c = W2@Wc, bc2 = b2@Wc + bc, BN affine --------
        int gid = bid * 256 + tid;                  // 0..2047
        int r = gid >> 4, c = gid & 15;
        float acc = 0.f;
#pragma unroll 8
        for (int k = 0; k < 128; k++) acc += W2[r * 128 + k] * Wc[k * 16 + c];
        W2c[gid] = acc;
        if (bid == 0) {
            if (tid < 16) {
                float a = bc[tid];
                for (int k = 0; k < 128; k++) a += b2[k] * Wc[k * 16 + tid];
                bc2[tid] = a;
            }
            if (tid < 64) {
                int c0 = tid * 2, c1 = c0 + 1;
                float sc0 = gamma[c0] * rsqrtf(rvar[c0] + BN_EPS);
                float sc1 = gamma[c1] * rsqrtf(rvar[c1] + BN_EPS);
                float sh0 = (b1[c0] - rmean[c0]) * sc0 + beta[c0];
                float sh1 = (b1[c1] - rmean[c1]) * sc1 + beta[c1];
                fusedq[tid] = make_float4(sc0, sh0, sc1, sh1);
            }
        }
    }
}

// ============ K1: ELL fill (blocks 0..624, FIRST) | MFMA gemm (625..1406) ============
// LDS is 32KB (hi frags only) -> 4 blocks/CU resident (vs 2 at 64KB): 2x latency hiding
// for BOTH the fill atomic chains and the gemm staging drain. lo frags are read straight
// from L2-hot global (coalesced dwordx4 per lane) inside the MFMA loop -- same values,
// same accumulation order, bit-identical output.
__global__ __launch_bounds__(256, 4) void gemm_fill_kernel(
        const float* __restrict__ seq, const bf16x8* __restrict__ WPK,
        unsigned* __restrict__ bufA,
        const int* __restrict__ eidx, int* __restrict__ deg, int* __restrict__ ell) {
    __shared__ __align__(16) char smem[32768];
    int tid = threadIdx.x;
    int bid = blockIdx.x;

    if (bid >= NBF) {
        int gb = bid - NBF;                         // gemm tile 0..781
        int w = tid >> 6, l = tid & 63;

        // -------- stage hi frags: 2048 x 16B chunks, linear LDS = linear global --------
        {
            const char* gsrc = (const char*)WPK;
#pragma unroll
            for (int r = 0; r < 8; r++)
                async_copy16(gsrc + (size_t)(r * 256 + tid) * 16,
                             smem + (r * 4 + w) * 1024);
        }

        // -------- x rows: load + hi/lo bf16 split (overlaps staging latency) --------
        int la = l & 15, q = l >> 4;
        int arow = gb * 64 + w * 16 + la;           // node this lane owns (output col)
        bool rowok = arow < N_NODES;
        const float4* X4 = (const float4*)seq;

        float4 xr[8];
        float4 z4 = make_float4(0.f, 0.f, 0.f, 0.f);
#pragma unroll
        for (int kt = 0; kt < 4; kt++) {
            xr[kt * 2]     = rowok ? X4[arow * 32 + kt * 8 + q * 2]     : z4;
            xr[kt * 2 + 1] = rowok ? X4[arow * 32 + kt * 8 + q * 2 + 1] : z4;
        }
        bf16x8 ah[4], al[4];
#pragma unroll
        for (int kt = 0; kt < 4; kt++) {
            const float* xv = (const float*)&xr[kt * 2];
#pragma unroll
            for (int j = 0; j < 8; j++) {
                float v = xv[j];
                unsigned short hs = bf16_rne(v);
                float rem = v - __uint_as_float(((unsigned)hs) << 16);
                ah[kt][j] = (short)hs;
                al[kt][j] = (short)bf16_rne(rem);
            }
        }
        f32x4 acc[8];
#pragma unroll
        for (int ct = 0; ct < 8; ct++) acc[ct] = (f32x4){0.f, 0.f, 0.f, 0.f};

        __syncthreads();                            // staging complete (drains vmcnt)

        const bf16x8* WH = (const bf16x8*)smem;     // 2048 hi frags (LDS)
        const bf16x8* WLg = WPK + 2048;             // 2048 lo frags (global, L2-hot)
#pragma unroll
        for (int kt = 0; kt < 4; kt++) {
#pragma unroll
            for (int ct = 0; ct < 8; ct++) {
                bf16x8 bh = WH[(ct * 4 + kt) * 64 + l];
                bf16x8 bl = WLg[(ct * 4 + kt) * 64 + l];
                acc[ct] = __builtin_amdgcn_mfma_f32_16x16x32_bf16(bh, ah[kt], acc[ct], 0, 0, 0);
                acc[ct] = __builtin_amdgcn_mfma_f32_16x16x32_bf16(bl, ah[kt], acc[ct], 0, 0, 0);
                acc[ct] = __builtin_amdgcn_mfma_f32_16x16x32_bf16(bh, al[kt], acc[ct], 0, 0, 0);
            }
        }

        // lane (la,q), reg r holds C[node arow][feat ct*16 + q*4 + r] -> pack pairs in-register
        if (rowok) {
            unsigned* dp = bufA + (size_t)arow * 64 + q * 2;
#pragma unroll
            for (int ct = 0; ct < 8; ct++) {
                uint2 u;
                u.x = pack_bf16x2(acc[ct][0], acc[ct][1]);
                u.y = pack_bf16x2(acc[ct][2], acc[ct][3]);
                *(uint2*)(dp + ct * 8) = u;
            }
        }
    } else {
        // -------- ELL fill: 4 edges/thread, count==slot from one atomicAdd --------
        const int4* src4 = (const int4*)eidx;
        const int4* dst4 = (const int4*)(eidx + N_EDGES);
        int t = bid * 256 + tid;
        int4 sv = src4[t];
        int4 dv = dst4[t];
        {
            int s = atomicAdd(&deg[dv.x], 1);
            if (s < ELLW) ell[dv.x * ELLW + s] = sv.x;
        }
        {
            int s = atomicAdd(&deg[dv.y], 1);
            if (s < ELLW) ell[dv.y * ELLW + s] = sv.y;
        }
        {
            int s = atomicAdd(&deg[dv.z], 1);
            if (s < ELLW) ell[dv.z * ELLW + s] = sv.z;
        }
        {
            int s = atomicAdd(&deg[dv.w], 1);
            if (s < ELLW) ell[dv.w * ELLW + s] = sv.w;
        }
    }
}

// ============ K2: layer-1 agg (1 wave/node) + BN + ReLU + @W2c -> Z ============
// Lane-parallel preamble: lane l holds edge l's src + weight (1 coalesced row load,
// 1 deg gather, 1 rsqrt for ALL 64 edges). Inner loop is shfl broadcasts + Hb gathers
// only -- no per-edge broadcast loads or rsqrts on the critical path. Tail is a uniform
// masked 8-batch (weights shfl'd as 0).
__global__ __launch_bounds__(256) void agg1_kernel(const unsigned* __restrict__ Hb,
                                                   const int* __restrict__ ell,
                                                   const int* __restrict__ deg,
                                                   const float4* __restrict__ fusedq,
                                                   const float* __restrict__ W2c,
                                                   float* __restrict__ Z) {
    __shared__ float sH[4][128];
    int w = threadIdx.x >> 6, l = threadIdx.x & 63;
    int node = blockIdx.x * 4 + w;             // 12500*4 == 50000
    int dgt = __builtin_amdgcn_readfirstlane(deg[node]);
    int dg = dgt < ELLW ? dgt : ELLW;          // loop bound (clamped)
    float di = rsqrtf((float)(dgt + 1));       // normalization uses TRUE degree
    const int* row = ell + node * ELLW;

    // per-lane edge prefetch: src + weight for edge l
    int s_l = (l < dg) ? row[l] : 0;
    float w_l = (l < dg) ? rsqrtf((float)(deg[s_l] + 1)) * di : 0.f;

    // W2c slice for the fused epilogue: lane (c=l&15, q=l>>4) owns k = q*32..+31 of column c
    int c = l & 15, q = l >> 4;
    float wreg[32];
#pragma unroll
    for (int i = 0; i < 32; i++) wreg[i] = W2c[(q * 32 + i) * 16 + c];

    unsigned hv = Hb[(size_t)node * 64 + l];
    float n2 = di * di;
    float acc0 = bf_lo(hv) * n2, acc1 = bf_hi(hv) * n2;  // self loop

    int dgr = (dg + 7) & ~7;                   // uniform masked 8-batches, no tail code
    for (int e = 0; e < dgr; e += 8) {
        int t0 = __shfl(s_l, e + 0), t1 = __shfl(s_l, e + 1);
        int t2 = __shfl(s_l, e + 2), t3 = __shfl(s_l, e + 3);
        int t4 = __shfl(s_l, e + 4), t5 = __shfl(s_l, e + 5);
        int t6 = __shfl(s_l, e + 6), t7 = __shfl(s_l, e + 7);
        float x0 = __shfl(w_l, e + 0), x1 = __shfl(w_l, e + 1);
        float x2 = __shfl(w_l, e + 2), x3 = __shfl(w_l, e + 3);
        float x4 = __shfl(w_l, e + 4), x5 = __shfl(w_l, e + 5);
        float x6 = __shfl(w_l, e + 6), x7 = __shfl(w_l, e + 7);
        unsigned u0 = Hb[(size_t)t0 * 64 + l];
        unsigned u1 = Hb[(size_t)t1 * 64 + l];
        unsigned u2 = Hb[(size_t)t2 * 64 + l];
        unsigned u3 = Hb[(size_t)t3 * 64 + l];
        unsigned u4 = Hb[(size_t)t4 * 64 + l];
        unsigned u5 = Hb[(size_t)t5 * 64 + l];
        unsigned u6 = Hb[(size_t)t6 * 64 + l];
        unsigned u7 = Hb[(size_t)t7 * 64 + l];
        acc0 += bf_lo(u0) * x0 + bf_lo(u1) * x1 + bf_lo(u2) * x2 + bf_lo(u3) * x3
              + bf_lo(u4) * x4 + bf_lo(u5) * x5 + bf_lo(u6) * x6 + bf_lo(u7) * x7;
        acc1 += bf_hi(u0) * x0 + bf_hi(u1) * x1 + bf_hi(u2) * x2 + bf_hi(u3) * x3
              + bf_hi(u4) * x4 + bf_hi(u5) * x5 + bf_hi(u6) * x6 + bf_hi(u7) * x7;
    }

    // fused BN affine + ReLU (lane l holds features 2l, 2l+1)
    float4 qv = fusedq[l];
    float a0 = fmaxf(acc0 * qv.x + qv.y, 0.f);
    float a1 = fmaxf(acc1 * qv.z + qv.w, 0.f);

    // in-wave transpose through LDS (wave-private region, no barrier)
    ((float2*)sH[w])[l] = make_float2(a0, a1);
    float z = 0.f;
    const float4* row4 = (const float4*)&sH[w][q * 32];
#pragma unroll
    for (int i = 0; i < 8; i++) {
        float4 v = row4[i];
        z += v.x * wreg[i * 4] + v.y * wreg[i * 4 + 1]
           + v.z * wreg[i * 4 + 2] + v.w * wreg[i * 4 + 3];
    }
    z += __shfl_xor(z, 16);
    z += __shfl_xor(z, 32);
    if (l < 16) Z[(size_t)node * NCLS + l] = z;
}

// ============ K3: layer-2 agg on Z (16-wide ELL) + bc2 -> out ============
// Same lane-parallel preamble with 4 static slot registers (16 edges each);
// 8 statically-unrolled predicated batches, shfl within the 16-lane group.
__global__ __launch_bounds__(256) void agg2_kernel(const float* __restrict__ Z,
                                                   const int* __restrict__ ell,
                                                   const int* __restrict__ deg,
                                                   const float* __restrict__ bc2,
                                                   float* __restrict__ out) {
    int tid = threadIdx.x;
    int c = tid & 15;
    int node = blockIdx.x * 16 + (tid >> 4);   // 3125*16 == 50000
    int lane = tid & 63;
    int baseln = lane & 48;                    // group base lane within the wave
    int dgt = deg[node];
    int dg = dgt < ELLW ? dgt : ELLW;
    float di = rsqrtf((float)(dgt + 1));
    const int* row = ell + node * ELLW;

    // slot s covers edges s*16..s*16+15; lane c holds edge s*16+c of its group
    int s0_ = (c < dg) ? row[c] : 0;
    int s1_ = (c + 16 < dg) ? row[c + 16] : 0;
    float w0_ = (c < dg) ? rsqrtf((float)(deg[s0_] + 1)) * di : 0.f;
    float w1_ = (c + 16 < dg) ? rsqrtf((float)(deg[s1_] + 1)) * di : 0.f;
    int s2_ = 0, s3_ = 0;
    float w2_ = 0.f, w3_ = 0.f;
    if (__any(dg > 32)) {                      // Poisson(12.8): almost never taken
        s2_ = (c + 32 < dg) ? row[c + 32] : 0;
        s3_ = (c + 48 < dg) ? row[c + 48] : 0;
        w2_ = (c + 32 < dg) ? rsqrtf((float)(deg[s2_] + 1)) * di : 0.f;
        w3_ = (c + 48 < dg) ? rsqrtf((float)(deg[s3_] + 1)) * di : 0.f;
    }

    float acc = Z[(size_t)node * NCLS + c] * di * di;

#define A2_BATCH(SS, WW, OFF)                                                        \
    {                                                                                \
        int t0 = __shfl(SS, baseln + OFF + 0), t1 = __shfl(SS, baseln + OFF + 1);    \
        int t2 = __shfl(SS, baseln + OFF + 2), t3 = __shfl(SS, baseln + OFF + 3);    \
        int t4 = __shfl(SS, baseln + OFF + 4), t5 = __shfl(SS, baseln + OFF + 5);    \
        int t6 = __shfl(SS, baseln + OFF + 6), t7 = __shfl(SS, baseln + OFF + 7);    \
        float x0 = __shfl(WW, baseln + OFF + 0), x1 = __shfl(WW, baseln + OFF + 1);  \
        float x2 = __shfl(WW, baseln + OFF + 2), x3 = __shfl(WW, baseln + OFF + 3);  \
        float x4 = __shfl(WW, baseln + OFF + 4), x5 = __shfl(WW, baseln + OFF + 5);  \
        float x6 = __shfl(WW, baseln + OFF + 6), x7 = __shfl(WW, baseln + OFF + 7);  \
        float v0 = Z[(size_t)t0 * NCLS + c];                                         \
        float v1 = Z[(size_t)t1 * NCLS + c];                                         \
        float v2 = Z[(size_t)t2 * NCLS + c];                                         \
        float v3 = Z[(size_t)t3 * NCLS + c];                                         \
        float v4 = Z[(size_t)t4 * NCLS + c];                                         \
        float v5 = Z[(size_t)t5 * NCLS + c];                                         \
        float v6 = Z[(size_t)t6 * NCLS + c];                                         \
        float v7 = Z[(size_t)t7 * NCLS + c];                                         \
        acc += v0 * x0 + v1 * x1 + v2 * x2 + v3 * x3                                 \
             + v4 * x4 + v5 * x5 + v6 * x6 + v7 * x7;                                \
    }

    if (dg > 0)  A2_BATCH(s0_, w0_, 0)
    if (dg > 8)  A2_BATCH(s0_, w0_, 8)
    if (dg > 16) A2_BATCH(s1_, w1_, 0)
    if (dg > 24) A2_BATCH(s1_, w1_, 8)
    if (dg > 32) A2_BATCH(s2_, w2_, 0)
    if (dg > 40) A2_BATCH(s2_, w2_, 8)
    if (dg > 48) A2_BATCH(s3_, w3_, 0)
    if (dg > 56) A2_BATCH(s3_, w3_, 8)
#undef A2_BATCH

    out[(size_t)node * NCLS + c] = acc + bc2[c];
}

// ---------------- Launch ----------------
extern "C" void kernel_launch(void* const* d_in, const int* in_sizes, int n_in,
                              void* d_out, int out_size, void* d_ws, size_t ws_size,
                              hipStream_t stream) {
    const float* seq   = (const float*)d_in[0];
    const int*   eidx  = (const int*)d_in[1];
    const float* W1    = (const float*)d_in[2];
    const float* b1    = (const float*)d_in[3];
    const float* gamma = (const float*)d_in[4];
    const float* beta  = (const float*)d_in[5];
    const float* rmean = (const float*)d_in[6];
    const float* rvar  = (const float*)d_in[7];
    const float* W2    = (const float*)d_in[8];
    const float* b2    = (const float*)d_in[9];
    const float* Wc    = (const float*)d_in[10];
    const float* bc    = (const float*)d_in[11];

    char* ws = (char*)d_ws;
    size_t off = 0;
    auto alloc = [&](size_t bytes) -> void* {
        void* p = ws + off;
        off = (off + bytes + 255) & ~(size_t)255;
        return p;
    };
    int*    deg      = (int*)alloc(50176 * 4);              // zeroed by K0 (uint4 x 12544)
    int*    ell      = (int*)alloc((size_t)N_NODES * ELLW * 4);   // 12.8 MB adjacency
    float*  W2c      = (float*)alloc(FDIM * NCLS * 4);
    float*  bc2      = (float*)alloc(NCLS * 4);
    float4* fusedq   = (float4*)alloc(64 * 16);
    unsigned* bufA   = (unsigned*)alloc((size_t)N_NODES * (FDIM / 2) * 4);  // bf16 packed
    float*  Zbuf     = (float*)alloc((size_t)N_NODES * NCLS * 4);
    bf16x8* WPK      = (bf16x8*)alloc(4096 * 16);           // packed W1 hi+lo frags (64KB)

    pack_fold_zero_kernel<<<16, 256, 0, stream>>>(
        W1, W2, Wc, b1, b2, bc, gamma, beta, rmean, rvar, WPK, W2c, bc2, fusedq,
        (uint4*)deg);
    gemm_fill_kernel<<<NBF + NBG, 256, 0, stream>>>(seq, WPK, bufA, eidx, deg, ell);
    agg1_kernel<<<N_NODES / 4, 256, 0, stream>>>(bufA, ell, deg, fusedq, W2c, Zbuf);
    agg2_kernel<<<N_NODES / 16, 256, 0, stream>>>(Zbuf, ell, deg, bc2, (float*)d_out);
}

// Round 10
// 186.320 us; speedup vs baseline: 1.0680x; 1.0680x over previous
//
#include <hip/hip_runtime.h>
#include <math.h>

#define N_NODES 50000
#define N_EDGES 640000
#define FDIM 128
#define NCLS 16
#define BN_EPS 1e-5f
#define NBG 391           // ceil(50000/128) gemm tiles (128 rows/block)
#define NBF 625           // fill blocks (4 edges/thread)
#define ELLW 64           // ELL row width (max degree; Poisson(12.8) -> P(>=64) ~ 1e-25)

typedef __attribute__((ext_vector_type(8))) short bf16x8;
typedef __attribute__((ext_vector_type(4))) float f32x4;

// ---- bf16 pack/unpack (RNE) ----
__device__ __forceinline__ unsigned pack_bf16x2(float lo, float hi) {
    unsigned ul = __float_as_uint(lo);
    unsigned uh = __float_as_uint(hi);
    ul += 0x7fff + ((ul >> 16) & 1);
    uh += 0x7fff + ((uh >> 16) & 1);
    return (ul >> 16) | (uh & 0xffff0000u);
}
__device__ __forceinline__ unsigned short bf16_rne(float x) {
    unsigned u = __float_as_uint(x);
    u += 0x7fff + ((u >> 16) & 1);
    return (unsigned short)(u >> 16);
}
__device__ __forceinline__ float bf_lo(unsigned u) { return __uint_as_float(u << 16); }
__device__ __forceinline__ float bf_hi(unsigned u) { return __uint_as_float(u & 0xffff0000u); }

// async 16B global->LDS copy: LDS dest = wave-uniform base + lane*16, global src per-lane
__device__ __forceinline__ void async_copy16(const void* g, void* l) {
    __builtin_amdgcn_global_load_lds(
        (const __attribute__((address_space(1))) unsigned*)g,
        (__attribute__((address_space(3))) unsigned*)l, 16, 0, 0);
}

// ============ K0: pack W1 frags + fold W2@Wc / BN affine + zero deg ============
// WPK layout: chunks 0..2047 = hi frags, 2048..4095 = lo frags (16B each, fragment order).
// frag index fi = ct*256 + kt*64 + lane; entry j: W1[kt*32+(lane>>4)*8+j][ct*16+(lane&15)]
__global__ __launch_bounds__(256) void pack_fold_zero_kernel(
        const float* __restrict__ W1, const float* __restrict__ W2,
        const float* __restrict__ Wc, const float* __restrict__ b1,
        const float* __restrict__ b2, const float* __restrict__ bc,
        const float* __restrict__ gamma, const float* __restrict__ beta,
        const float* __restrict__ rmean, const float* __restrict__ rvar,
        bf16x8* __restrict__ WPK,
        float* __restrict__ W2c, float* __restrict__ bc2, float4* __restrict__ fusedq,
        uint4* __restrict__ degz) {
    int tid = threadIdx.x;
    int bid = blockIdx.x;

    // -------- zero deg[] (50176 ints = 12544 uint4) across all 16 blocks --------
    {
        int gz = bid * 256 + tid;                   // 0..4095
#pragma unroll
        for (int i = 0; i < 4; i++) {
            int idx = gz + i * 4096;
            if (idx < 12544) degz[idx] = make_uint4(0, 0, 0, 0);
        }
    }

    if (bid >= 8) {
        // -------- pack W1: blocks 8..15, one fragment per thread --------
        int fi = (bid - 8) * 256 + tid;             // 0..2047
        int lane = fi & 63, kt = (fi >> 6) & 3, ct = fi >> 8;
        int kbase = kt * 32 + (lane >> 4) * 8;
        int col = ct * 16 + (lane & 15);
        short h[8], lo[8];
#pragma unroll
        for (int j = 0; j < 8; j++) {
            float wv = W1[(kbase + j) * 128 + col];
            unsigned short hs = bf16_rne(wv);
            float rem = wv - __uint_as_float(((unsigned)hs) << 16);
            h[j] = (short)hs;
            lo[j] = (short)bf16_rne(rem);
        }
        WPK[fi] = *(bf16x8*)h;
        WPK[2048 + fi] = *(bf16x8*)lo;
    } else {
        // -------- fold: W2c = W2@Wc, bc2 = b2@Wc + bc, BN affine --------
        int gid = bid * 256 + tid;                  // 0..2047
        int r = gid >> 4, c = gid & 15;
        float acc = 0.f;
#pragma unroll 8
        for (int k = 0; k < 128; k++) acc += W2[r * 128 + k] * Wc[k * 16 + c];
        W2c[gid] = acc;
        if (bid == 0) {
            if (tid < 16) {
                float a = bc[tid];
                for (int k = 0; k < 128; k++) a += b2[k] * Wc[k * 16 + tid];
                bc2[tid] = a;
            }
            if (tid < 64) {
                int c0 = tid * 2, c1 = c0 + 1;
                float sc0 = gamma[c0] * rsqrtf(rvar[c0] + BN_EPS);
                float sc1 = gamma[c1] * rsqrtf(rvar[c1] + BN_EPS);
                float sh0 = (b1[c0] - rmean[c0]) * sc0 + beta[c0];
                float sh1 = (b1[c1] - rmean[c1]) * sc1 + beta[c1];
                fusedq[tid] = make_float4(sc0, sh0, sc1, sh1);
            }
        }
    }
}

// ============ K1: ELL fill (blocks 0..624, FIRST) | MFMA gemm 128-row tiles (625..1015) ============
// Round-8 lesson: occupancy was NOT the bound (2x waves -> slower). The bound is per-block
// serial work: W staging L2 traffic + fill atomic chains. So: M-tile 128 halves the gemm
// block count and the W-staging bytes per output row; each bh/bl LDS read now feeds 6 MFMAs
// (two independent row-subtiles) -- 2x MFMA:LDS density, dual acc chains pipeline the MFMA
// latency. VGPR ~180 is free (LDS caps residency at 2 blocks/CU; <=256 VGPR keeps 8 waves).
__global__ __launch_bounds__(256) void gemm_fill_kernel(
        const float* __restrict__ seq, const bf16x8* __restrict__ WPK,
        unsigned* __restrict__ bufA,
        const int* __restrict__ eidx, int* __restrict__ deg, int* __restrict__ ell) {
    __shared__ __align__(16) char smem[65536];
    int tid = threadIdx.x;
    int bid = blockIdx.x;

    if (bid >= NBF) {
        int gb = bid - NBF;                         // gemm tile 0..390
        int w = tid >> 6, l = tid & 63;

        // -------- stage hi+lo frags: 4096 x 16B chunks, linear LDS = linear global --------
        {
            const char* gsrc = (const char*)WPK;
#pragma unroll
            for (int r = 0; r < 16; r++)
                async_copy16(gsrc + (size_t)(r * 256 + tid) * 16,
                             smem + (r * 4 + w) * 1024);
        }

        // -------- x rows for BOTH subtiles: load + hi/lo split (overlaps staging) --------
        int la = l & 15, q = l >> 4;
        int rb = gb * 128 + w * 16;
        int arow0 = rb + la;                        // subtile 0 row
        int arow1 = rb + 64 + la;                   // subtile 1 row
        bool ok0 = arow0 < N_NODES, ok1 = arow1 < N_NODES;
        const float4* X4 = (const float4*)seq;

        float4 xr0[8], xr1[8];
        float4 z4 = make_float4(0.f, 0.f, 0.f, 0.f);
#pragma unroll
        for (int kt = 0; kt < 4; kt++) {
            xr0[kt * 2]     = ok0 ? X4[arow0 * 32 + kt * 8 + q * 2]     : z4;
            xr0[kt * 2 + 1] = ok0 ? X4[arow0 * 32 + kt * 8 + q * 2 + 1] : z4;
            xr1[kt * 2]     = ok1 ? X4[arow1 * 32 + kt * 8 + q * 2]     : z4;
            xr1[kt * 2 + 1] = ok1 ? X4[arow1 * 32 + kt * 8 + q * 2 + 1] : z4;
        }
        bf16x8 ah0[4], al0[4], ah1[4], al1[4];
#pragma unroll
        for (int kt = 0; kt < 4; kt++) {
            const float* xv0 = (const float*)&xr0[kt * 2];
            const float* xv1 = (const float*)&xr1[kt * 2];
#pragma unroll
            for (int j = 0; j < 8; j++) {
                float v = xv0[j];
                unsigned short hs = bf16_rne(v);
                ah0[kt][j] = (short)hs;
                al0[kt][j] = (short)bf16_rne(v - __uint_as_float(((unsigned)hs) << 16));
                float u = xv1[j];
                unsigned short hs1 = bf16_rne(u);
                ah1[kt][j] = (short)hs1;
                al1[kt][j] = (short)bf16_rne(u - __uint_as_float(((unsigned)hs1) << 16));
            }
        }
        f32x4 acc0[8], acc1[8];
#pragma unroll
        for (int ct = 0; ct < 8; ct++) {
            acc0[ct] = (f32x4){0.f, 0.f, 0.f, 0.f};
            acc1[ct] = (f32x4){0.f, 0.f, 0.f, 0.f};
        }

        __syncthreads();                            // staging complete (drains vmcnt)

        const bf16x8* WH = (const bf16x8*)smem;           // 2048 hi frags
        const bf16x8* WL = (const bf16x8*)(smem + 32768); // 2048 lo frags
#pragma unroll
        for (int kt = 0; kt < 4; kt++) {
#pragma unroll
            for (int ct = 0; ct < 8; ct++) {
                bf16x8 bh = WH[(ct * 4 + kt) * 64 + l];
                bf16x8 bl = WL[(ct * 4 + kt) * 64 + l];
                acc0[ct] = __builtin_amdgcn_mfma_f32_16x16x32_bf16(bh, ah0[kt], acc0[ct], 0, 0, 0);
                acc1[ct] = __builtin_amdgcn_mfma_f32_16x16x32_bf16(bh, ah1[kt], acc1[ct], 0, 0, 0);
                acc0[ct] = __builtin_amdgcn_mfma_f32_16x16x32_bf16(bl, ah0[kt], acc0[ct], 0, 0, 0);
                acc1[ct] = __builtin_amdgcn_mfma_f32_16x16x32_bf16(bl, ah1[kt], acc1[ct], 0, 0, 0);
                acc0[ct] = __builtin_amdgcn_mfma_f32_16x16x32_bf16(bh, al0[kt], acc0[ct], 0, 0, 0);
                acc1[ct] = __builtin_amdgcn_mfma_f32_16x16x32_bf16(bh, al1[kt], acc1[ct], 0, 0, 0);
            }
        }

        // lane (la,q), reg r holds C[row][feat ct*16 + q*4 + r] -> pack pairs in-register
        if (ok0) {
            unsigned* dp = bufA + (size_t)arow0 * 64 + q * 2;
#pragma unroll
            for (int ct = 0; ct < 8; ct++) {
                uint2 u;
                u.x = pack_bf16x2(acc0[ct][0], acc0[ct][1]);
                u.y = pack_bf16x2(acc0[ct][2], acc0[ct][3]);
                *(uint2*)(dp + ct * 8) = u;
            }
        }
        if (ok1) {
            unsigned* dp = bufA + (size_t)arow1 * 64 + q * 2;
#pragma unroll
            for (int ct = 0; ct < 8; ct++) {
                uint2 u;
                u.x = pack_bf16x2(acc1[ct][0], acc1[ct][1]);
                u.y = pack_bf16x2(acc1[ct][2], acc1[ct][3]);
                *(uint2*)(dp + ct * 8) = u;
            }
        }
    } else {
        // -------- ELL fill: 4 edges/thread, count==slot from one atomicAdd --------
        const int4* src4 = (const int4*)eidx;
        const int4* dst4 = (const int4*)(eidx + N_EDGES);
        int t = bid * 256 + tid;
        int4 sv = src4[t];
        int4 dv = dst4[t];
        {
            int s = atomicAdd(&deg[dv.x], 1);
            if (s < ELLW) ell[dv.x * ELLW + s] = sv.x;
        }
        {
            int s = atomicAdd(&deg[dv.y], 1);
            if (s < ELLW) ell[dv.y * ELLW + s] = sv.y;
        }
        {
            int s = atomicAdd(&deg[dv.z], 1);
            if (s < ELLW) ell[dv.z * ELLW + s] = sv.z;
        }
        {
            int s = atomicAdd(&deg[dv.w], 1);
            if (s < ELLW) ell[dv.w * ELLW + s] = sv.w;
        }
    }
}

// ============ K2: layer-1 agg (1 wave/node) + BN + ReLU + @W2c -> Z ============
// Lane-parallel preamble: lane l holds edge l's src + weight (1 coalesced row load,
// 1 deg gather, 1 rsqrt for ALL 64 edges). Inner loop is shfl broadcasts + Hb gathers
// only -- no per-edge broadcast loads or rsqrts on the critical path. Tail is a uniform
// masked 8-batch (weights shfl'd as 0).
__global__ __launch_bounds__(256) void agg1_kernel(const unsigned* __restrict__ Hb,
                                                   const int* __restrict__ ell,
                                                   const int* __restrict__ deg,
                                                   const float4* __restrict__ fusedq,
                                                   const float* __restrict__ W2c,
                                                   float* __restrict__ Z) {
    __shared__ float sH[4][128];
    int w = threadIdx.x >> 6, l = threadIdx.x & 63;
    int node = blockIdx.x * 4 + w;             // 12500*4 == 50000
    int dgt = __builtin_amdgcn_readfirstlane(deg[node]);
    int dg = dgt < ELLW ? dgt : ELLW;          // loop bound (clamped)
    float di = rsqrtf((float)(dgt + 1));       // normalization uses TRUE degree
    const int* row = ell + node * ELLW;

    // per-lane edge prefetch: src + weight for edge l
    int s_l = (l < dg) ? row[l] : 0;
    float w_l = (l < dg) ? rsqrtf((float)(deg[s_l] + 1)) * di : 0.f;

    // W2c slice for the fused epilogue: lane (c=l&15, q=l>>4) owns k = q*32..+31 of column c
    int c = l & 15, q = l >> 4;
    float wreg[32];
#pragma unroll
    for (int i = 0; i < 32; i++) wreg[i] = W2c[(q * 32 + i) * 16 + c];

    unsigned hv = Hb[(size_t)node * 64 + l];
    float n2 = di * di;
    float acc0 = bf_lo(hv) * n2, acc1 = bf_hi(hv) * n2;  // self loop

    int dgr = (dg + 7) & ~7;                   // uniform masked 8-batches, no tail code
    for (int e = 0; e < dgr; e += 8) {
        int t0 = __shfl(s_l, e + 0), t1 = __shfl(s_l, e + 1);
        int t2 = __shfl(s_l, e + 2), t3 = __shfl(s_l, e + 3);
        int t4 = __shfl(s_l, e + 4), t5 = __shfl(s_l, e + 5);
        int t6 = __shfl(s_l, e + 6), t7 = __shfl(s_l, e + 7);
        float x0 = __shfl(w_l, e + 0), x1 = __shfl(w_l, e + 1);
        float x2 = __shfl(w_l, e + 2), x3 = __shfl(w_l, e + 3);
        float x4 = __shfl(w_l, e + 4), x5 = __shfl(w_l, e + 5);
        float x6 = __shfl(w_l, e + 6), x7 = __shfl(w_l, e + 7);
        unsigned u0 = Hb[(size_t)t0 * 64 + l];
        unsigned u1 = Hb[(size_t)t1 * 64 + l];
        unsigned u2 = Hb[(size_t)t2 * 64 + l];
        unsigned u3 = Hb[(size_t)t3 * 64 + l];
        unsigned u4 = Hb[(size_t)t4 * 64 + l];
        unsigned u5 = Hb[(size_t)t5 * 64 + l];
        unsigned u6 = Hb[(size_t)t6 * 64 + l];
        unsigned u7 = Hb[(size_t)t7 * 64 + l];
        acc0 += bf_lo(u0) * x0 + bf_lo(u1) * x1 + bf_lo(u2) * x2 + bf_lo(u3) * x3
              + bf_lo(u4) * x4 + bf_lo(u5) * x5 + bf_lo(u6) * x6 + bf_lo(u7) * x7;
        acc1 += bf_hi(u0) * x0 + bf_hi(u1) * x1 + bf_hi(u2) * x2 + bf_hi(u3) * x3
              + bf_hi(u4) * x4 + bf_hi(u5) * x5 + bf_hi(u6) * x6 + bf_hi(u7) * x7;
    }

    // fused BN affine + ReLU (lane l holds features 2l, 2l+1)
    float4 qv = fusedq[l];
    float a0 = fmaxf(acc0 * qv.x + qv.y, 0.f);
    float a1 = fmaxf(acc1 * qv.z + qv.w, 0.f);

    // in-wave transpose through LDS (wave-private region, no barrier)
    ((float2*)sH[w])[l] = make_float2(a0, a1);
    float z = 0.f;
    const float4* row4 = (const float4*)&sH[w][q * 32];
#pragma unroll
    for (int i = 0; i < 8; i++) {
        float4 v = row4[i];
        z += v.x * wreg[i * 4] + v.y * wreg[i * 4 + 1]
           + v.z * wreg[i * 4 + 2] + v.w * wreg[i * 4 + 3];
    }
    z += __shfl_xor(z, 16);
    z += __shfl_xor(z, 32);
    if (l < 16) Z[(size_t)node * NCLS + l] = z;
}

// ============ K3: layer-2 agg on Z (16-wide ELL) + bc2 -> out ============
// Same lane-parallel preamble with 4 static slot registers (16 edges each);
// 8 statically-unrolled predicated batches, shfl within the 16-lane group.
__global__ __launch_bounds__(256) void agg2_kernel(const float* __restrict__ Z,
                                                   const int* __restrict__ ell,
                                                   const int* __restrict__ deg,
                                                   const float* __restrict__ bc2,
                                                   float* __restrict__ out) {
    int tid = threadIdx.x;
    int c = tid & 15;
    int node = blockIdx.x * 16 + (tid >> 4);   // 3125*16 == 50000
    int lane = tid & 63;
    int baseln = lane & 48;                    // group base lane within the wave
    int dgt = deg[node];
    int dg = dgt < ELLW ? dgt : ELLW;
    float di = rsqrtf((float)(dgt + 1));
    const int* row = ell + node * ELLW;

    // slot s covers edges s*16..s*16+15; lane c holds edge s*16+c of its group
    int s0_ = (c < dg) ? row[c] : 0;
    int s1_ = (c + 16 < dg) ? row[c + 16] : 0;
    float w0_ = (c < dg) ? rsqrtf((float)(deg[s0_] + 1)) * di : 0.f;
    float w1_ = (c + 16 < dg) ? rsqrtf((float)(deg[s1_] + 1)) * di : 0.f;
    int s2_ = 0, s3_ = 0;
    float w2_ = 0.f, w3_ = 0.f;
    if (__any(dg > 32)) {                      // Poisson(12.8): almost never taken
        s2_ = (c + 32 < dg) ? row[c + 32] : 0;
        s3_ = (c + 48 < dg) ? row[c + 48] : 0;
        w2_ = (c + 32 < dg) ? rsqrtf((float)(deg[s2_] + 1)) * di : 0.f;
        w3_ = (c + 48 < dg) ? rsqrtf((float)(deg[s3_] + 1)) * di : 0.f;
    }

    float acc = Z[(size_t)node * NCLS + c] * di * di;

#define A2_BATCH(SS, WW, OFF)                                                        \
    {                                                                                \
        int t0 = __shfl(SS, baseln + OFF + 0), t1 = __shfl(SS, baseln + OFF + 1);    \
        int t2 = __shfl(SS, baseln + OFF + 2), t3 = __shfl(SS, baseln + OFF + 3);    \
        int t4 = __shfl(SS, baseln + OFF + 4), t5 = __shfl(SS, baseln + OFF + 5);    \
        int t6 = __shfl(SS, baseln + OFF + 6), t7 = __shfl(SS, baseln + OFF + 7);    \
        float x0 = __shfl(WW, baseln + OFF + 0), x1 = __shfl(WW, baseln + OFF + 1);  \
        float x2 = __shfl(WW, baseln + OFF + 2), x3 = __shfl(WW, baseln + OFF + 3);  \
        float x4 = __shfl(WW, baseln + OFF + 4), x5 = __shfl(WW, baseln + OFF + 5);  \
        float x6 = __shfl(WW, baseln + OFF + 6), x7 = __shfl(WW, baseln + OFF + 7);  \
        float v0 = Z[(size_t)t0 * NCLS + c];                                         \
        float v1 = Z[(size_t)t1 * NCLS + c];                                         \
        float v2 = Z[(size_t)t2 * NCLS + c];                                         \
        float v3 = Z[(size_t)t3 * NCLS + c];                                         \
        float v4 = Z[(size_t)t4 * NCLS + c];                                         \
        float v5 = Z[(size_t)t5 * NCLS + c];                                         \
        float v6 = Z[(size_t)t6 * NCLS + c];                                         \
        float v7 = Z[(size_t)t7 * NCLS + c];                                         \
        acc += v0 * x0 + v1 * x1 + v2 * x2 + v3 * x3                                 \
             + v4 * x4 + v5 * x5 + v6 * x6 + v7 * x7;                                \
    }

    if (dg > 0)  A2_BATCH(s0_, w0_, 0)
    if (dg > 8)  A2_BATCH(s0_, w0_, 8)
    if (dg > 16) A2_BATCH(s1_, w1_, 0)
    if (dg > 24) A2_BATCH(s1_, w1_, 8)
    if (dg > 32) A2_BATCH(s2_, w2_, 0)
    if (dg > 40) A2_BATCH(s2_, w2_, 8)
    if (dg > 48) A2_BATCH(s3_, w3_, 0)
    if (dg > 56) A2_BATCH(s3_, w3_, 8)
#undef A2_BATCH

    out[(size_t)node * NCLS + c] = acc + bc2[c];
}

// ---------------- Launch ----------------
extern "C" void kernel_launch(void* const* d_in, const int* in_sizes, int n_in,
                              void* d_out, int out_size, void* d_ws, size_t ws_size,
                              hipStream_t stream) {
    const float* seq   = (const float*)d_in[0];
    const int*   eidx  = (const int*)d_in[1];
    const float* W1    = (const float*)d_in[2];
    const float* b1    = (const float*)d_in[3];
    const float* gamma = (const float*)d_in[4];
    const float* beta  = (const float*)d_in[5];
    const float* rmean = (const float*)d_in[6];
    const float* rvar  = (const float*)d_in[7];
    const float* W2    = (const float*)d_in[8];
    const float* b2    = (const float*)d_in[9];
    const float* Wc    = (const float*)d_in[10];
    const float* bc    = (const float*)d_in[11];

    char* ws = (char*)d_ws;
    size_t off = 0;
    auto alloc = [&](size_t bytes) -> void* {
        void* p = ws + off;
        off = (off + bytes + 255) & ~(size_t)255;
        return p;
    };
    int*    deg      = (int*)alloc(50176 * 4);              // zeroed by K0 (uint4 x 12544)
    int*    ell      = (int*)alloc((size_t)N_NODES * ELLW * 4);   // 12.8 MB adjacency
    float*  W2c      = (float*)alloc(FDIM * NCLS * 4);
    float*  bc2      = (float*)alloc(NCLS * 4);
    float4* fusedq   = (float4*)alloc(64 * 16);
    unsigned* bufA   = (unsigned*)alloc((size_t)N_NODES * (FDIM / 2) * 4);  // bf16 packed
    float*  Zbuf     = (float*)alloc((size_t)N_NODES * NCLS * 4);
    bf16x8* WPK      = (bf16x8*)alloc(4096 * 16);           // packed W1 hi+lo frags (64KB)

    pack_fold_zero_kernel<<<16, 256, 0, stream>>>(
        W1, W2, Wc, b1, b2, bc, gamma, beta, rmean, rvar, WPK, W2c, bc2, fusedq,
        (uint4*)deg);
    gemm_fill_kernel<<<NBF + NBG, 256, 0, stream>>>(seq, WPK, bufA, eidx, deg, ell);
    agg1_kernel<<<N_NODES / 4, 256, 0, stream>>>(bufA, ell, deg, fusedq, W2c, Zbuf);
    agg2_kernel<<<N_NODES / 16, 256, 0, stream>>>(Zbuf, ell, deg, bc2, (float*)d_out);
}